// Round 5
// baseline (164.176 us; speedup 1.0000x reference)
//
#include <hip/hip_runtime.h>
#include <hip/hip_bf16.h>

// RPN head: conv3x3(512->512)+ReLU, then 1x1 cls(18)+2-way softmax and 1x1 bbox(36).
// conv = bf16 MFMA implicit GEMM, 256x256 tile, 8 waves, BK=32 TRIPLE-buffered LDS,
// counted s_waitcnt vmcnt(4) at tile boundaries (never full-drain in steady state).

typedef __bf16 bf16_t;
typedef __attribute__((ext_vector_type(8))) __bf16 bf16x8;
typedef __attribute__((ext_vector_type(4))) __bf16 bf16x4;
typedef __attribute__((ext_vector_type(4))) float f32x4;

#define HW 3800
#define NPOS (8 * HW)
#define XP_IMG (52 * 78 * 512)

__device__ __forceinline__ void gload_lds16(const bf16_t* g, char* l) {
  __builtin_amdgcn_global_load_lds(
      (const __attribute__((address_space(1))) unsigned int*)g,
      (__attribute__((address_space(3))) unsigned int*)l, 16, 0, 0);
}

// base_feat [8][512][50][76] f32 -> Xp [8][52][78][512] bf16.
__global__ __launch_bounds__(256) void pad_nhwc(const float* __restrict__ x,
                                                bf16_t* __restrict__ Xp) {
  const int t = threadIdx.x;
  const int blk = blockIdx.x;
  if (blk < 1600) {
    __shared__ __align__(16) bf16_t tile[76][136];  // [w][c], 272B rows
    const int cb = blk & 3;
    int r = blk >> 2;
    const int h = r % 50, b = r / 50;
#pragma unroll
    for (int it = 0; it < 10; ++it) {
      int idx = it * 256 + t;
      if (idx < 2432) {
        int c = idx / 19, w4 = idx - c * 19;
        const float4 v = *(const float4*)(x +
            (((size_t)(b * 512 + cb * 128 + c)) * 50 + h) * 76 + w4 * 4);
        tile[w4 * 4 + 0][c] = (bf16_t)v.x;
        tile[w4 * 4 + 1][c] = (bf16_t)v.y;
        tile[w4 * 4 + 2][c] = (bf16_t)v.z;
        tile[w4 * 4 + 3][c] = (bf16_t)v.w;
      }
    }
    __syncthreads();
#pragma unroll
    for (int it = 0; it < 5; ++it) {
      int idx = it * 256 + t;
      if (idx < 1216) {
        int w = idx >> 4, c8 = idx & 15;
        bf16x8 v = *(const bf16x8*)&tile[w][c8 * 8];
        *(bf16x8*)(Xp + ((size_t)(b * 52 + h + 1) * 78 + (w + 1)) * 512 +
                   cb * 128 + c8 * 8) = v;
      }
    }
  } else {
    const int blk2 = blk - 1600;            // 16 halo blocks
    const int b = blk2 >> 1, half = blk2 & 1;
    bf16x8 z;
#pragma unroll
    for (int j = 0; j < 8; ++j) z[j] = (bf16_t)0.f;
#pragma unroll
    for (int it = 0; it < 32; ++it) {
      int idx = it * 256 + t;
      int q = half * 128 + (idx >> 6);
      int c8 = idx & 63;
      int h, w;
      if (q < 78)       { h = 0;           w = q; }
      else if (q < 156) { h = 51;          w = q - 78; }
      else if (q < 206) { h = q - 156 + 1; w = 0; }
      else              { h = q - 206 + 1; w = 77; }
      *(bf16x8*)(Xp + ((size_t)(b * 52 + h) * 78 + w) * 512 + c8 * 8) = z;
    }
  }
}

// conv_w [512][512][3][3] f32 -> Wt [9][co][ci] bf16.
__global__ __launch_bounds__(256) void wtrans(const float* __restrict__ cw,
                                              bf16_t* __restrict__ Wt) {
  __shared__ bf16_t lw[4608];
  const int t = threadIdx.x;
  const int co = blockIdx.x;
  const float* src = cw + (size_t)co * 4608;
#pragma unroll
  for (int it = 0; it < 18; ++it) {
    int idx = it * 256 + t;
    lw[idx] = (bf16_t)src[idx];
  }
  __syncthreads();
#pragma unroll
  for (int s = 0; s < 9; ++s) {
    int ci = t * 2;
    bf16_t v0 = lw[ci * 9 + s], v1 = lw[(ci + 1) * 9 + s];
    bf16_t* dst = Wt + ((size_t)s * 512 + co) * 512 + ci;
    dst[0] = v0; dst[1] = v1;
  }
}

// cls_w [18][512], bbox_w [36][512] f32 -> Whb [64][512] bf16, rows permuted.
__global__ __launch_bounds__(256) void whb_build(const float* __restrict__ clsw,
                                                 const float* __restrict__ boxw,
                                                 bf16_t* __restrict__ Whb) {
  int t = blockIdx.x * 256 + threadIdx.x;   // 64*512 = 32768
  int ci = t & 511; int row = t >> 9;
  float v = 0.f;
  if (row < 18) {
    int a = row >> 1, logit = row & 1;
    v = clsw[(logit * 9 + a) * 512 + ci];
  } else if (row < 54) {
    v = boxw[(row - 18) * 512 + ci];
  }
  Whb[(size_t)row * 512 + ci] = (bf16_t)v;
}

// implicit-GEMM conv3x3: 256co x 256pos tile, BK=32, 8 waves (2Mx4N),
// triple-buffered 96KiB LDS, counted-vmcnt pipeline over 144 K-tiles.
__global__ __launch_bounds__(512) void conv3x3(const bf16_t* __restrict__ Xp,
                                               const bf16_t* __restrict__ Wt,
                                               const float* __restrict__ convb,
                                               bf16_t* __restrict__ rc2) {
  // buffer k (k=0,1,2) at 32768*k: A[0,16K) B[16K,32K)
  __shared__ __align__(16) char smem[98304];
  const int tid = threadIdx.x;
  const int lane = tid & 63;
  const int wv = tid >> 6;          // 0..7
  const int wm = wv >> 2;           // 0..1  (co half)
  const int wn = wv & 3;            // 0..3  (pos quarter)
  const int lm = lane & 15, lg = lane >> 4;

  // XCD swizzle: 240 blocks, 240%8==0 -> one image per XCD
  const int raw = blockIdx.x;
  const int wg = (raw & 7) * 30 + (raw >> 3);
  const int b = wg / 30;
  const int rem = wg - b * 30;
  const int co_base = (rem & 1) * 256;
  const int pos_base = (rem >> 1) * 256;

  // staging descriptors: chunk d = i*512+tid (0..1023); LDS row r=d>>2 (64B rows),
  // phys chunk p=d&3, logical chunk c = p ^ ((r>>1)&3)  (pre-swizzled SOURCE).
  int aSrcRow[2], hB2[2], wB2[2], cB2[2];
#pragma unroll
  for (int i = 0; i < 2; ++i) {
    int d = i * 512 + tid;
    int r = d >> 2, p = d & 3, c = p ^ ((r >> 1) & 3);
    aSrcRow[i] = (co_base + r) * 512 + c * 8;
    int m = pos_base + r; if (m > HW - 1) m = HW - 1;   // tail clamp (masked at store)
    hB2[i] = m / 76; wB2[i] = m - (m / 76) * 76; cB2[i] = c * 8;
  }
  const bf16_t* XpB = Xp + (size_t)b * XP_IMG;

  // fragment read offsets: row*64 + swizzled k-chunk (2-way bank pattern = free)
  const int koff = (lg ^ ((lm >> 1) & 3)) << 4;
  int aOffF[8], bOffF[4];
#pragma unroll
  for (int m = 0; m < 8; ++m) aOffF[m] = (wm * 128 + m * 16 + lm) * 64 + koff;
#pragma unroll
  for (int n = 0; n < 4; ++n) bOffF[n] = 16384 + (wn * 64 + n * 16 + lm) * 64 + koff;

  f32x4 acc[8][4];
#pragma unroll
  for (int i = 0; i < 8; ++i)
#pragma unroll
    for (int j = 0; j < 4; ++j) acc[i][j] = (f32x4){0.f, 0.f, 0.f, 0.f};

#define ISSUE_STAGE(KT, BASE) {                                                   \
    const int s_ = (KT) >> 4, cb_ = (KT) & 15;                                    \
    const int kh_ = s_ / 3, kw_ = s_ - kh_ * 3;                                   \
    const bf16_t* As_ = Wt + (size_t)s_ * 262144 + cb_ * 32;                      \
    _Pragma("unroll")                                                             \
    for (int i = 0; i < 2; ++i)                                                   \
      gload_lds16(As_ + aSrcRow[i], smem + (BASE) + (i * 512 + tid) * 16);        \
    _Pragma("unroll")                                                             \
    for (int i = 0; i < 2; ++i)                                                   \
      gload_lds16(XpB + ((hB2[i] + kh_) * 78 + (wB2[i] + kw_)) * 512 + cB2[i] +   \
                      cb_ * 32,                                                   \
                  smem + (BASE) + 16384 + (i * 512 + tid) * 16);                  \
  }

#define TILE(KT, CURB, NXTB, DO_ISSUE, LAST) {                                    \
    if (DO_ISSUE) ISSUE_STAGE((KT) + 2, NXTB);                                    \
    const char* Ab_ = smem + (CURB);                                              \
    bf16x8 pb_[4], pa_[4];                                                        \
    _Pragma("unroll")                                                             \
    for (int n = 0; n < 4; ++n) pb_[n] = *(const bf16x8*)(Ab_ + bOffF[n]);        \
    _Pragma("unroll")                                                             \
    for (int f = 0; f < 4; ++f) pa_[f] = *(const bf16x8*)(Ab_ + aOffF[f]);        \
    __builtin_amdgcn_s_setprio(1);                                                \
    _Pragma("unroll")                                                             \
    for (int f = 0; f < 4; ++f)                                                   \
      _Pragma("unroll")                                                           \
      for (int n = 0; n < 4; ++n)                                                 \
        acc[f][n] = __builtin_amdgcn_mfma_f32_16x16x32_bf16(pa_[f], pb_[n],       \
                                                            acc[f][n], 0, 0, 0); \
    __builtin_amdgcn_s_setprio(0);                                                \
    _Pragma("unroll")                                                             \
    for (int f = 0; f < 4; ++f) pa_[f] = *(const bf16x8*)(Ab_ + aOffF[4 + f]);    \
    __builtin_amdgcn_s_setprio(1);                                                \
    _Pragma("unroll")                                                             \
    for (int f = 0; f < 4; ++f)                                                   \
      _Pragma("unroll")                                                           \
      for (int n = 0; n < 4; ++n)                                                 \
        acc[4 + f][n] = __builtin_amdgcn_mfma_f32_16x16x32_bf16(pa_[f], pb_[n],   \
                                                          acc[4 + f][n], 0, 0, 0);\
    __builtin_amdgcn_s_setprio(0);                                                \
    if (!(LAST)) {                                                                \
      if (DO_ISSUE) { asm volatile("s_waitcnt vmcnt(4)" ::: "memory"); }          \
      else          { asm volatile("s_waitcnt vmcnt(0)" ::: "memory"); }          \
      __builtin_amdgcn_s_barrier();                                               \
      __builtin_amdgcn_sched_barrier(0);                                          \
    }                                                                             \
  }

  // prologue: stage tiles 0,1 into buf0,buf1; wait tile0 only (counted)
  ISSUE_STAGE(0, 0);
  ISSUE_STAGE(1, 32768);
  asm volatile("s_waitcnt vmcnt(4)" ::: "memory");
  __builtin_amdgcn_s_barrier();
  __builtin_amdgcn_sched_barrier(0);

  for (int kt = 0; kt < 141; kt += 3) {    // tiles 0..140 (kt%3==0 at loop head)
    TILE(kt + 0, 0,     65536, true, false);
    TILE(kt + 1, 32768, 0,     true, false);
    TILE(kt + 2, 65536, 32768, true, false);
  }
  TILE(141, 0,     65536, true,  false);   // issues stage(143)
  TILE(142, 32768, 0,     false, false);   // drains stage(143) via vmcnt(0)
  TILE(143, 65536, 32768, false, true);    // last tile: no boundary needed

#undef TILE
#undef ISSUE_STAGE

  // epilogue: bias + ReLU, store NHWC rc2[(b*HW+pos)][co], 8B per fragment
  const size_t outRow = (size_t)b * HW;
#pragma unroll
  for (int m = 0; m < 8; ++m) {
    const int co = co_base + wm * 128 + m * 16 + lg * 4;
    const float4 bias = *(const float4*)(convb + co);
#pragma unroll
    for (int n = 0; n < 4; ++n) {
      const int pos = pos_base + wn * 64 + n * 16 + lm;
      if (pos < HW) {
        bf16x4 v;
        float z0 = acc[m][n][0] + bias.x; v[0] = (bf16_t)(z0 > 0.f ? z0 : 0.f);
        float z1 = acc[m][n][1] + bias.y; v[1] = (bf16_t)(z1 > 0.f ? z1 : 0.f);
        float z2 = acc[m][n][2] + bias.z; v[2] = (bf16_t)(z2 > 0.f ? z2 : 0.f);
        float z3 = acc[m][n][3] + bias.w; v[3] = (bf16_t)(z3 > 0.f ? z3 : 0.f);
        *(bf16x4*)(rc2 + (outRow + pos) * 512 + co) = v;
      }
    }
  }
}

// heads: C[64co][128pos] = Whb[64][512] x rc2[pos][512], fused bias/softmax/store.
__global__ __launch_bounds__(256) void heads_mfma(const bf16_t* __restrict__ rc2,
                                                  const bf16_t* __restrict__ Whb,
                                                  const float* __restrict__ clsb,
                                                  const float* __restrict__ boxb,
                                                  float* __restrict__ out) {
  __shared__ __align__(16) char smem[24576];  // A:[0,8K) B:[8K,24K)
  const int t = threadIdx.x, lane = t & 63, wv = t >> 6;
  const int lm = lane & 15, lg = lane >> 4, lx = lane & 7;
  const int pos_base = blockIdx.x * 128;

  int aSrc[2], bSrc[4];
#pragma unroll
  for (int i = 0; i < 2; ++i) {
    int d = i * 256 + t;
    int r = d >> 3, p = d & 7, c = p ^ (r & 7);
    aSrc[i] = r * 512 + c * 8;
  }
#pragma unroll
  for (int i = 0; i < 4; ++i) {
    int d = i * 256 + t;
    int r = d >> 3, p = d & 7, c = p ^ (r & 7);
    int pg = pos_base + r; if (pg > NPOS - 1) pg = NPOS - 1;
    bSrc[i] = pg * 512 + c * 8;
  }

  f32x4 acc[4][2];
#pragma unroll
  for (int i = 0; i < 4; ++i)
#pragma unroll
    for (int j = 0; j < 2; ++j) acc[i][j] = (f32x4){0.f, 0.f, 0.f, 0.f};

  for (int cb = 0; cb < 8; ++cb) {
    __syncthreads();
#pragma unroll
    for (int i = 0; i < 2; ++i) {
      int d = i * 256 + t;
      gload_lds16(Whb + aSrc[i] + cb * 64, &smem[d * 16]);
    }
#pragma unroll
    for (int i = 0; i < 4; ++i) {
      int d = i * 256 + t;
      gload_lds16(rc2 + (size_t)bSrc[i] + cb * 64, &smem[8192 + d * 16]);
    }
    __syncthreads();
#pragma unroll
    for (int ks = 0; ks < 2; ++ks) {
      const int koff = ((ks * 4 + lg) ^ lx) << 4;
      bf16x8 af[4], bfr[2];
#pragma unroll
      for (int f = 0; f < 4; ++f)
        af[f] = *(const bf16x8*)&smem[(f * 16 + lm) * 128 + koff];
#pragma unroll
      for (int f = 0; f < 2; ++f)
        bfr[f] = *(const bf16x8*)&smem[8192 + (wv * 32 + f * 16 + lm) * 128 + koff];
#pragma unroll
      for (int fa = 0; fa < 4; ++fa)
#pragma unroll
        for (int fb = 0; fb < 2; ++fb)
          acc[fa][fb] = __builtin_amdgcn_mfma_f32_16x16x32_bf16(
              af[fa], bfr[fb], acc[fa][fb], 0, 0, 0);
    }
  }

  float* boxOut = out + (size_t)8 * 18 * HW;
#pragma unroll
  for (int fb = 0; fb < 2; ++fb) {
    const int pg = pos_base + wv * 32 + fb * 16 + lm;
    if (pg < NPOS) {
      const int b = pg / HW;
      const int m = pg - b * HW;
#pragma unroll
      for (int fa = 0; fa < 4; ++fa) {
        const int base = fa * 16 + lg * 4;
#pragma unroll
        for (int pr = 0; pr < 2; ++pr) {
          const int row0 = base + pr * 2;
          const float v0 = acc[fa][fb][pr * 2];
          const float v1 = acc[fa][fb][pr * 2 + 1];
          if (row0 < 18) {
            const int a = row0 >> 1;
            const float s0 = v0 + clsb[a];
            const float s1 = v1 + clsb[9 + a];
            const float mx = fmaxf(s0, s1);
            const float e0 = expf(s0 - mx), e1 = expf(s1 - mx);
            const float inv = 1.0f / (e0 + e1);
            out[((size_t)(b * 18 + a)) * HW + m] = e0 * inv;
            out[((size_t)(b * 18 + 9 + a)) * HW + m] = e1 * inv;
          } else if (row0 < 54) {
            const int c0 = row0 - 18;
            boxOut[((size_t)(b * 36 + c0)) * HW + m] = v0 + boxb[c0];
            boxOut[((size_t)(b * 36 + c0 + 1)) * HW + m] = v1 + boxb[c0 + 1];
          }
        }
      }
    }
  }
}

extern "C" void kernel_launch(void* const* d_in, const int* in_sizes, int n_in,
                              void* d_out, int out_size, void* d_ws, size_t ws_size,
                              hipStream_t stream) {
  (void)in_sizes; (void)n_in; (void)out_size; (void)ws_size;
  const float* base_feat = (const float*)d_in[0];
  const float* conv_w = (const float*)d_in[4];
  const float* conv_b = (const float*)d_in[5];
  const float* cls_w  = (const float*)d_in[6];
  const float* cls_b  = (const float*)d_in[7];
  const float* bbox_w = (const float*)d_in[8];
  const float* bbox_b = (const float*)d_in[9];

  char* ws = (char*)d_ws;
  bf16_t* Xp  = (bf16_t*)(ws);                 // 8*52*78*512*2   = 33,226,752 B
  bf16_t* Wt  = (bf16_t*)(ws + 33226752);      // 9*512*512*2     =  4,718,592 B
  bf16_t* rc2 = (bf16_t*)(ws + 37945344);      // 30400*512*2     = 31,129,600 B (NHWC)
  bf16_t* Whb = (bf16_t*)(ws + 69074944);      // 64*512*2        =     65,536 B

  hipLaunchKernelGGL(pad_nhwc,   dim3(1616), dim3(256), 0, stream, base_feat, Xp);
  hipLaunchKernelGGL(wtrans,     dim3(512),  dim3(256), 0, stream, conv_w, Wt);
  hipLaunchKernelGGL(whb_build,  dim3(128),  dim3(256), 0, stream, cls_w, bbox_w, Whb);
  hipLaunchKernelGGL(conv3x3,    dim3(240),  dim3(512), 0, stream, Xp, Wt, conv_b, rc2);
  hipLaunchKernelGGL(heads_mfma, dim3(238),  dim3(256), 0, stream, rc2, Whb, cls_b, bbox_b,
                     (float*)d_out);
}